// Round 4
// baseline (2152.856 us; speedup 1.0000x reference)
//
#include <hip/hip_runtime.h>
#include <math.h>

// QMIX mixing network, fused single kernel, fp32.
// B=131072, STATE=256, HYPER=256, EMBED=64, AGENTS=8.
// lane==row (TILE=64 rows/block); 16 waves (1024 thr) split output columns.
// Activations in LDS (padded stride PST=260 breaks pow2 banking);
// weights wave-uniform -> scalar s_load broadcast; FMA inner loops.
// FP32 VALU roofline ~520us (no fp32 MFMA on CDNA4). LDS 134KB -> 1 block/CU,
// 16 waves/CU = 4 waves/SIMD (needs VGPR<=128).

#define NA   8
#define SDIM 256
#define HDIM 256
#define EDIM 64
#define TILE 64
#define PST  260   // padded LDS row stride in floats
#define WPB  16    // waves per block
#define CA   (HDIM / WPB)   // 16 hyper cols per wave
#define CE   (EDIM / WPB)   // 4 embed cols per wave

__global__ __launch_bounds__(1024, 2)
void qmix_fused(const float* __restrict__ agent_qs,
                const float* __restrict__ states,
                const float* __restrict__ w1a, const float* __restrict__ b1a,
                const float* __restrict__ w1b, const float* __restrict__ b1b,
                const float* __restrict__ wfa, const float* __restrict__ bfa,
                const float* __restrict__ wfb, const float* __restrict__ bfb,
                const float* __restrict__ wb1, const float* __restrict__ bb1,
                const float* __restrict__ wva, const float* __restrict__ bva,
                const float* __restrict__ wvb, const float* __restrict__ bvb,
                float* __restrict__ out)
{
    extern __shared__ float lds[];
    float* sS = lds;                    // [TILE][PST] states tile
    float* sH = lds + TILE * PST;       // [TILE][PST] h1 / hf tile
    float* sY = lds + 2 * TILE * PST;   // [WPB][64] per-wave partial y

    const int tid = threadIdx.x;
    const int w   = tid >> 6;           // wave 0..15
    const int l   = tid & 63;           // lane == local row
    const long long r0 = (long long)blockIdx.x * TILE;

    // ---- stage states tile into LDS (coalesced float4, padded rows) ----
    {
        const float4* g = (const float4*)(states + r0 * SDIM);
        #pragma unroll
        for (int j = 0; j < 4; ++j) {
            int f = tid + j * 1024;         // 0..4095 float4s
            int r = f >> 6, q = f & 63;
            float4 v = g[f];
            *(float4*)&sS[r * PST + q * 4] = v;
        }
    }
    // per-lane agent_qs (row = lane)
    float qs[NA];
    {
        const float4* gq = (const float4*)(agent_qs + (r0 + l) * NA);
        float4 a = gq[0], b = gq[1];
        qs[0]=a.x; qs[1]=a.y; qs[2]=a.z; qs[3]=a.w;
        qs[4]=b.x; qs[5]=b.y; qs[6]=b.z; qs[7]=b.w;
    }
    __syncthreads();

    // ---- stage 2: h1 = relu(states@w1a + b1a) ; wave w -> cols [CA*w, CA*w+CA) ----
    {
        const int cb = __builtin_amdgcn_readfirstlane(w * CA);
        float acc[CA];
        #pragma unroll
        for (int c = 0; c < CA; ++c) acc[c] = 0.f;
        const float* srow = &sS[l * PST];
        for (int kb = 0; kb < SDIM; kb += 4) {
            float4 a4 = *(const float4*)&srow[kb];
            float av[4] = {a4.x, a4.y, a4.z, a4.w};
            const float* wp = w1a + (size_t)kb * HDIM + cb;
            #pragma unroll
            for (int kr = 0; kr < 4; ++kr)
                #pragma unroll
                for (int c = 0; c < CA; ++c)
                    acc[c] = fmaf(av[kr], wp[kr * HDIM + c], acc[c]);
        }
        #pragma unroll
        for (int c = 0; c < CA; ++c)
            sH[l * PST + cb + c] = fmaxf(acc[c] + b1a[cb + c], 0.f);
    }
    __syncthreads();

    // ---- stage 3: w1 = |h1@w1b + b1b|, mixed with qs on the fly ----
    // wave w -> embed cols [CE*w, CE*w+CE), all 8 agents. acc[agent][eo]
    float mix[CE];
    {
        const int eb = __builtin_amdgcn_readfirstlane(w * CE);
        float acc[NA * CE];
        #pragma unroll
        for (int i = 0; i < NA * CE; ++i) acc[i] = 0.f;
        const float* hrow = &sH[l * PST];
        for (int kb = 0; kb < HDIM; kb += 4) {
            float4 a4 = *(const float4*)&hrow[kb];
            float av[4] = {a4.x, a4.y, a4.z, a4.w};
            #pragma unroll
            for (int kr = 0; kr < 4; ++kr) {
                const float* wp = w1b + (size_t)(kb + kr) * (NA * EDIM) + eb;
                #pragma unroll
                for (int ag = 0; ag < NA; ++ag)
                    #pragma unroll
                    for (int eo = 0; eo < CE; ++eo)
                        acc[ag * CE + eo] = fmaf(av[kr], wp[ag * EDIM + eo], acc[ag * CE + eo]);
            }
        }
        #pragma unroll
        for (int eo = 0; eo < CE; ++eo) mix[eo] = 0.f;
        #pragma unroll
        for (int ag = 0; ag < NA; ++ag) {
            float q = qs[ag];
            #pragma unroll
            for (int eo = 0; eo < CE; ++eo)
                mix[eo] += q * fabsf(acc[ag * CE + eo] + b1b[ag * EDIM + eb + eo]);
        }
    }
    __syncthreads();   // all waves done reading sH before stage 5 overwrites it

    // ---- stage 4: b1 = states@wb1 + bb1 ; hidden = elu(mix + b1) ----
    float hid[CE];
    {
        const int eb = __builtin_amdgcn_readfirstlane(w * CE);
        float acc[CE];
        #pragma unroll
        for (int i = 0; i < CE; ++i) acc[i] = 0.f;
        const float* srow = &sS[l * PST];
        for (int kb = 0; kb < SDIM; kb += 4) {
            float4 a4 = *(const float4*)&srow[kb];
            float av[4] = {a4.x, a4.y, a4.z, a4.w};
            #pragma unroll
            for (int kr = 0; kr < 4; ++kr) {
                const float* wp = wb1 + (size_t)(kb + kr) * EDIM + eb;
                #pragma unroll
                for (int eo = 0; eo < CE; ++eo)
                    acc[eo] = fmaf(av[kr], wp[eo], acc[eo]);
            }
        }
        #pragma unroll
        for (int eo = 0; eo < CE; ++eo) {
            float x = mix[eo] + acc[eo] + bb1[eb + eo];
            hid[eo] = x > 0.f ? x : expm1f(x);
        }
    }

    // ---- stage 5: hf = relu(states@wfa + bfa) -> sH ----
    {
        const int cb = __builtin_amdgcn_readfirstlane(w * CA);
        float acc[CA];
        #pragma unroll
        for (int c = 0; c < CA; ++c) acc[c] = 0.f;
        const float* srow = &sS[l * PST];
        for (int kb = 0; kb < SDIM; kb += 4) {
            float4 a4 = *(const float4*)&srow[kb];
            float av[4] = {a4.x, a4.y, a4.z, a4.w};
            const float* wp = wfa + (size_t)kb * HDIM + cb;
            #pragma unroll
            for (int kr = 0; kr < 4; ++kr)
                #pragma unroll
                for (int c = 0; c < CA; ++c)
                    acc[c] = fmaf(av[kr], wp[kr * HDIM + c], acc[c]);
        }
        #pragma unroll
        for (int c = 0; c < CA; ++c)
            sH[l * PST + cb + c] = fmaxf(acc[c] + bfa[cb + c], 0.f);
    }
    __syncthreads();

    // ---- stage 6: w_final = |hf@wfb + bfb| ----
    float wf[CE];
    {
        const int eb = __builtin_amdgcn_readfirstlane(w * CE);
        float acc[CE];
        #pragma unroll
        for (int i = 0; i < CE; ++i) acc[i] = 0.f;
        const float* hrow = &sH[l * PST];
        for (int kb = 0; kb < HDIM; kb += 4) {
            float4 a4 = *(const float4*)&hrow[kb];
            float av[4] = {a4.x, a4.y, a4.z, a4.w};
            #pragma unroll
            for (int kr = 0; kr < 4; ++kr) {
                const float* wp = wfb + (size_t)(kb + kr) * EDIM + eb;
                #pragma unroll
                for (int eo = 0; eo < CE; ++eo)
                    acc[eo] = fmaf(av[kr], wp[eo], acc[eo]);
            }
        }
        #pragma unroll
        for (int eo = 0; eo < CE; ++eo)
            wf[eo] = fabsf(acc[eo] + bfb[eb + eo]);
    }

    // ---- stage 7: hv = relu(states@wva + bva); y partials ----
    float py = 0.f;
    {
        const int eb = __builtin_amdgcn_readfirstlane(w * CE);
        float acc[CE];
        #pragma unroll
        for (int i = 0; i < CE; ++i) acc[i] = 0.f;
        const float* srow = &sS[l * PST];
        for (int kb = 0; kb < SDIM; kb += 4) {
            float4 a4 = *(const float4*)&srow[kb];
            float av[4] = {a4.x, a4.y, a4.z, a4.w};
            #pragma unroll
            for (int kr = 0; kr < 4; ++kr) {
                const float* wp = wva + (size_t)(kb + kr) * EDIM + eb;
                #pragma unroll
                for (int eo = 0; eo < CE; ++eo)
                    acc[eo] = fmaf(av[kr], wp[eo], acc[eo]);
            }
        }
        #pragma unroll
        for (int eo = 0; eo < CE; ++eo) {
            float hv = fmaxf(acc[eo] + bva[eb + eo], 0.f);
            py = fmaf(hv, wvb[eb + eo], py);      // V-head partial
            py = fmaf(hid[eo], wf[eo], py);       // mixing dot partial
        }
    }
    sY[w * 64 + l] = py;
    __syncthreads();

    if (w == 0) {
        float y = bvb[0];
        #pragma unroll
        for (int i = 0; i < WPB; ++i) y += sY[i * 64 + l];
        out[r0 + l] = y;
    }
}

extern "C" void kernel_launch(void* const* d_in, const int* in_sizes, int n_in,
                              void* d_out, int out_size, void* d_ws, size_t ws_size,
                              hipStream_t stream)
{
    const float* agent_qs = (const float*)d_in[0];
    const float* states   = (const float*)d_in[1];
    const float* w1a = (const float*)d_in[2];
    const float* b1a = (const float*)d_in[3];
    const float* w1b = (const float*)d_in[4];
    const float* b1b = (const float*)d_in[5];
    const float* wfa = (const float*)d_in[6];
    const float* bfa = (const float*)d_in[7];
    const float* wfb = (const float*)d_in[8];
    const float* bfb = (const float*)d_in[9];
    const float* wb1 = (const float*)d_in[10];
    const float* bb1 = (const float*)d_in[11];
    const float* wva = (const float*)d_in[12];
    const float* bva = (const float*)d_in[13];
    const float* wvb = (const float*)d_in[14];
    const float* bvb = (const float*)d_in[15];
    float* out = (float*)d_out;

    const int B = in_sizes[0] / NA;           // 131072
    const size_t shmem = (size_t)(2 * TILE * PST + WPB * 64) * sizeof(float); // ~134 KB

    hipFuncSetAttribute((const void*)qmix_fused,
                        hipFuncAttributeMaxDynamicSharedMemorySize, (int)shmem);

    qmix_fused<<<B / TILE, 1024, shmem, stream>>>(
        agent_qs, states, w1a, b1a, w1b, b1b, wfa, bfa, wfb, bfb,
        wb1, bb1, wva, bva, wvb, bvb, out);
}

// Round 5
// 637.905 us; speedup vs baseline: 3.3749x; 3.3749x over previous
//
#include <hip/hip_runtime.h>
#include <hip/hip_bf16.h>
#include <math.h>

// QMIX fused MFMA kernel. B=131072, STATE=256, HYPER=256, EMBED=64, A=8.
// K1: pack weights f32->bf16 MFMA B-frag chunks in d_ws (re-packed every call).
// K2: 64-row tile, 8 waves, phases:
//  0: states f32 -> bf16 sA (XOR-swizzled), qs -> sQ
//  1: H1 = relu(S@W1a+b1a) -> sH (bf16)   [MFMA 16x16x32]
//  2: sMix = S@Wb1 + bb1                   (f32, per-element owner)
//  3: sMix += q_a * |H1@W1b + b1b|        (ds_add_f32 cross-wave agent sum)
//  4: Hf = relu(S@Wfa+bfa) -> sH
//  5: sWf = |Hf@Wfb+bfb| ; sHv = relu(S@Wva+bva)
//  6: y = sum_e elu(sMix)*sWf + sHv*wvb + bvb
// Frag convention (m89/m92-verified): A row=lane&15, 8 contiguous k per lane
// (k-chunk lane>>4); B col=lane&15 same k-map (consistent permutation => exact);
// D col=lane&15, row=(lane>>4)*4+reg.

#define NA 8
#define SDIM 256
#define TM 64
#define PADE 66

#define OW1A 0
#define OW1B 65536
#define OWFA 196608
#define OWB1 262144
#define OWFB 278528
#define OWVA 294912
#define NPACK 311296

typedef __attribute__((ext_vector_type(8))) short short8;
typedef __attribute__((ext_vector_type(4))) float f32x4;

__device__ inline unsigned short bfu(float x) {
    __hip_bfloat16 h = __float2bfloat16(x);
    unsigned short u; __builtin_memcpy(&u, &h, 2); return u;
}

__device__ inline f32x4 mfma16(short8 a, short8 b, f32x4 c) {
    return __builtin_amdgcn_mfma_f32_16x16x32_bf16(a, b, c, 0, 0, 0);
}

// swizzled bf16 A-frag read: row*512B + kstep*64B + kgroup*16B, XOR (row&7)<<4
__device__ inline short8 ldfrag(const char* base, int row, int s, int g) {
    int off = (row * 512 + s * 64 + g * 16) ^ ((row & 7) << 4);
    return *(const short8*)(base + off);
}

// ---------- kernel 1: weight packing ----------
// chunk(s,t) = s*(N/16)+t -> 512 bf16: lane l elem j = W[s*32+(l>>4)*8+j][t*16+(l&15)]
__global__ void pack_weights(const float* __restrict__ w1a, const float* __restrict__ w1b,
                             const float* __restrict__ wfa, const float* __restrict__ wb1,
                             const float* __restrict__ wfb, const float* __restrict__ wva,
                             unsigned short* __restrict__ dst)
{
    int tid = blockIdx.x * 256 + threadIdx.x;
    if (tid >= NPACK) return;
    const float* src; int N; int local;
    if      (tid < OW1B) { src = w1a; N = 256; local = tid;        }
    else if (tid < OWFA) { src = w1b; N = 512; local = tid - OW1B; }
    else if (tid < OWB1) { src = wfa; N = 256; local = tid - OWFA; }
    else if (tid < OWFB) { src = wb1; N = 64;  local = tid - OWB1; }
    else if (tid < OWVA) { src = wfb; N = 64;  local = tid - OWFB; }
    else                 { src = wva; N = 64;  local = tid - OWVA; }
    int c    = local >> 9;
    int rem  = local & 511;
    int lane = rem >> 3;
    int j    = rem & 7;
    int tn   = N >> 4;
    int s    = c / tn, t = c - s * tn;
    int k = s * 32 + (lane >> 4) * 8 + j;
    int n = t * 16 + (lane & 15);
    dst[tid] = bfu(src[(size_t)k * N + n]);
}

// ---------- big GEMM [64,256] -> relu -> bf16 sOut ----------
__device__ inline void gemm_h(const char* sIn, char* sOut,
                              const unsigned short* pk, const float* __restrict__ bias,
                              int w, int l, int lg, int lm)
{
    f32x4 acc[4][2];
    #pragma unroll
    for (int tm = 0; tm < 4; ++tm)
        #pragma unroll
        for (int tl = 0; tl < 2; ++tl) acc[tm][tl] = (f32x4){0.f, 0.f, 0.f, 0.f};
    #pragma unroll 2
    for (int s = 0; s < 8; ++s) {
        short8 bfr[2];
        #pragma unroll
        for (int tl = 0; tl < 2; ++tl)
            bfr[tl] = ((const short8*)(pk + (s * 16 + 2 * w + tl) * 512))[l];
        #pragma unroll
        for (int tm = 0; tm < 4; ++tm) {
            short8 afr = ldfrag(sIn, tm * 16 + lm, s, lg);
            acc[tm][0] = mfma16(afr, bfr[0], acc[tm][0]);
            acc[tm][1] = mfma16(afr, bfr[1], acc[tm][1]);
        }
    }
    #pragma unroll
    for (int tl = 0; tl < 2; ++tl) {
        int col = (2 * w + tl) * 16 + lm;
        float b = bias[col];
        #pragma unroll
        for (int tm = 0; tm < 4; ++tm)
            #pragma unroll
            for (int r = 0; r < 4; ++r) {
                int row = tm * 16 + lg * 4 + r;
                int off = (row * 512 + col * 2) ^ ((row & 7) << 4);
                *(unsigned short*)(sOut + off) = bfu(fmaxf(acc[tm][tl][r] + b, 0.f));
            }
    }
}

// ---------- small GEMM [64,64] -> f32 sOut. MODE 0 plain, 1 abs, 2 relu ----------
template<int MODE>
__device__ inline void gemm_e(const char* sIn, float* sOut,
                              const unsigned short* pk, const float* __restrict__ bias,
                              int w, int l, int lg, int lm)
{
    int tn  = w & 3;
    int tm0 = (w >> 2) * 2;
    f32x4 acc[2];
    acc[0] = (f32x4){0.f, 0.f, 0.f, 0.f};
    acc[1] = (f32x4){0.f, 0.f, 0.f, 0.f};
    #pragma unroll
    for (int s = 0; s < 8; ++s) {
        short8 bfr = ((const short8*)(pk + (s * 4 + tn) * 512))[l];
        #pragma unroll
        for (int i = 0; i < 2; ++i) {
            short8 afr = ldfrag(sIn, (tm0 + i) * 16 + lm, s, lg);
            acc[i] = mfma16(afr, bfr, acc[i]);
        }
    }
    int col = tn * 16 + lm;
    float b = bias[col];
    #pragma unroll
    for (int i = 0; i < 2; ++i)
        #pragma unroll
        for (int r = 0; r < 4; ++r) {
            int row = (tm0 + i) * 16 + lg * 4 + r;
            float v = acc[i][r] + b;
            if (MODE == 1) v = fabsf(v);
            if (MODE == 2) v = fmaxf(v, 0.f);
            sOut[row * PADE + col] = v;
        }
}

// ---------- kernel 2: fused QMIX ----------
__global__ __launch_bounds__(512, 2)
void qmix_mfma(const float* __restrict__ agent_qs, const float* __restrict__ states,
               const float* __restrict__ b1a, const float* __restrict__ b1b,
               const float* __restrict__ bfa, const float* __restrict__ bfb,
               const float* __restrict__ bb1, const float* __restrict__ bva,
               const float* __restrict__ wvb, const float* __restrict__ bvb,
               const unsigned short* __restrict__ pk, float* __restrict__ out)
{
    extern __shared__ char lds[];
    char*  sA   = lds;                          // [64][256] bf16, swizzled (32KB)
    char*  sH   = lds + 32768;                  // [64][256] bf16, swizzled (32KB)
    float* sMix = (float*)(lds + 65536);        // [64][66] f32
    float* sWf  = sMix + TM * PADE;
    float* sHv  = sWf + TM * PADE;
    float* sQ   = sHv + TM * PADE;              // [64][8] f32

    const int tid = threadIdx.x;
    const int w  = tid >> 6, l = tid & 63;
    const int lg = l >> 4,  lm = l & 15;
    // XCD-aware bijective swizzle (grid=2048, %8==0)
    const int sb = ((int)blockIdx.x & 7) * ((int)gridDim.x >> 3) + ((int)blockIdx.x >> 3);
    const long long r0 = (long long)sb * TM;

    // ---- phase 0: stage states (f32->bf16 swizzled) + qs ----
    {
        const float4* g = (const float4*)(states + r0 * SDIM);
        #pragma unroll
        for (int jj = 0; jj < 8; ++jj) {
            int f = tid + jj * 512;             // 4096 float4s
            int row = f >> 6, q = f & 63;
            float4 v = g[f];
            unsigned lo = (unsigned)bfu(v.x) | ((unsigned)bfu(v.y) << 16);
            unsigned hi = (unsigned)bfu(v.z) | ((unsigned)bfu(v.w) << 16);
            int off = (row * 512 + q * 8) ^ ((row & 7) << 4);
            *(uint2*)(sA + off) = make_uint2(lo, hi);
        }
        sQ[tid] = agent_qs[r0 * NA + tid];      // 64 rows x 8 agents, coalesced
    }
    __syncthreads();

    // ---- phase 1: H1 -> sH ; phase 2: sMix = S@Wb1 + bb1 ----
    gemm_h(sA, sH, pk + OW1A, b1a, w, l, lg, lm);
    gemm_e<0>(sA, sMix, pk + OWB1, bb1, w, l, lg, lm);
    __syncthreads();

    // ---- phase 3: sMix += q_w * |H1@W1b + b1b| (wave w = agent w) ----
    {
        f32x4 acc[4][4];
        #pragma unroll
        for (int tm = 0; tm < 4; ++tm)
            #pragma unroll
            for (int tl = 0; tl < 4; ++tl) acc[tm][tl] = (f32x4){0.f, 0.f, 0.f, 0.f};
        #pragma unroll 2
        for (int s = 0; s < 8; ++s) {
            short8 bfr[4];
            #pragma unroll
            for (int tl = 0; tl < 4; ++tl)
                bfr[tl] = ((const short8*)(pk + OW1B + (s * 32 + 4 * w + tl) * 512))[l];
            #pragma unroll
            for (int tm = 0; tm < 4; ++tm) {
                short8 afr = ldfrag(sH, tm * 16 + lm, s, lg);
                #pragma unroll
                for (int tl = 0; tl < 4; ++tl)
                    acc[tm][tl] = mfma16(afr, bfr[tl], acc[tm][tl]);
            }
        }
        #pragma unroll
        for (int tl = 0; tl < 4; ++tl) {
            int e = tl * 16 + lm;
            float b = b1b[w * 64 + e];
            #pragma unroll
            for (int tm = 0; tm < 4; ++tm)
                #pragma unroll
                for (int r = 0; r < 4; ++r) {
                    int row = tm * 16 + lg * 4 + r;
                    atomicAdd(&sMix[row * PADE + e],
                              sQ[row * 8 + w] * fabsf(acc[tm][tl][r] + b));
                }
        }
    }
    __syncthreads();

    // ---- phase 4: Hf -> sH ----
    gemm_h(sA, sH, pk + OWFA, bfa, w, l, lg, lm);
    __syncthreads();

    // ---- phase 5: wf = |Hf@Wfb+bfb| ; hv = relu(S@Wva+bva) ----
    gemm_e<1>(sH, sWf, pk + OWFB, bfb, w, l, lg, lm);
    gemm_e<2>(sA, sHv, pk + OWVA, bva, w, l, lg, lm);
    __syncthreads();

    // ---- phase 6: y = sum_e elu(mix)*wf + hv*wvb + bvb ----
    {
        int r  = w * 8 + (l >> 3);
        int j0 = (l & 7) * 8;
        float py = 0.f;
        #pragma unroll
        for (int j = 0; j < 8; ++j) {
            float m = sMix[r * PADE + j0 + j];
            float hid = m > 0.f ? m : expm1f(m);
            py = fmaf(hid, sWf[r * PADE + j0 + j], py);
            py = fmaf(sHv[r * PADE + j0 + j], wvb[j0 + j], py);
        }
        py += __shfl_xor(py, 1);
        py += __shfl_xor(py, 2);
        py += __shfl_xor(py, 4);
        if ((l & 7) == 0) out[r0 + r] = py + bvb[0];
    }
}

extern "C" void kernel_launch(void* const* d_in, const int* in_sizes, int n_in,
                              void* d_out, int out_size, void* d_ws, size_t ws_size,
                              hipStream_t stream)
{
    const float* agent_qs = (const float*)d_in[0];
    const float* states   = (const float*)d_in[1];
    const float* w1a = (const float*)d_in[2];
    const float* b1a = (const float*)d_in[3];
    const float* w1b = (const float*)d_in[4];
    const float* b1b = (const float*)d_in[5];
    const float* wfa = (const float*)d_in[6];
    const float* bfa = (const float*)d_in[7];
    const float* wfb = (const float*)d_in[8];
    const float* bfb = (const float*)d_in[9];
    const float* wb1 = (const float*)d_in[10];
    const float* bb1 = (const float*)d_in[11];
    const float* wva = (const float*)d_in[12];
    const float* bva = (const float*)d_in[13];
    const float* wvb = (const float*)d_in[14];
    const float* bvb = (const float*)d_in[15];
    float* out = (float*)d_out;
    unsigned short* packed = (unsigned short*)d_ws;

    const int B = in_sizes[0] / NA;             // 131072

    pack_weights<<<(NPACK + 255) / 256, 256, 0, stream>>>(
        w1a, w1b, wfa, wb1, wfb, wva, packed);

    const size_t shmem = 65536 + (size_t)(3 * TM * PADE + TM * NA) * sizeof(float); // 118272
    hipFuncSetAttribute((const void*)qmix_mfma,
                        hipFuncAttributeMaxDynamicSharedMemorySize, (int)shmem);

    qmix_mfma<<<B / TM, 512, shmem, stream>>>(
        agent_qs, states, b1a, b1b, bfa, bfb, bb1, bva, wvb, bvb, packed, out);
}